// Round 17
// baseline (423.153 us; speedup 1.0000x reference)
//
#include <hip/hip_runtime.h>
#include <math.h>

#define NN 1024
#define IN_F 256
#define OUT_F 128
#define NHEADS 4
#define NHF 32
#define ITILE 4
#define HPSTR 260  // h-tile row stride in dwords; conflict-free b128 floor.
#define MAGIC 0x13570246u

typedef float vf2 __attribute__((ext_vector_type(2)));  // -> v_pk_*_f32 on gfx950

// Fused GAT v2 (R13 confound removed).
// R13's 4.5x regression signature (FETCH 212MB / WRITE 199MB) was ITILE=8
// scratch spill under the 64-VGPR cap -- the same mechanism as R4 -- NOT the
// barrier: the barrier passed and did not deadlock at grid 512. This version:
//   - ITILE=4 (proven ~45-50 live VGPRs) + launch_bounds(512,4) => cap 128,
//     zero spill risk. LDS 24.8KB => 2 blocks/CU with margin; R2 vs R4 showed
//     16 waves/CU == 32 waves/CU for this workload (both 42us), so the lower
//     occupancy costs nothing.
//   - Part 1: 2 GEMM tiles/block (1024 tiles of 16 rows x 16 cols).
//   - Software barrier: release-fence + per-block MAGIC flag in d_ws (poison
//     refill re-arms each iteration; stale MAGIC is benign since glh/grh are
//     pure functions of constant inputs).
//   - Part 2: 2 attention units/block of the proven v6 ITILE=4 body.
// Purpose is double: remove the inter-kernel launch gap AND make the single
// dispatch large enough (>41us fills) to finally surface in the top-5 profile
// with real counters if the kernels are as slow as the accounting implies.
__device__ __attribute__((aligned(16))) float g_glh[NHEADS * NN * NHF];
__device__ __attribute__((aligned(16))) float g_grh[NHEADS * NN * NHF];

#define LDS_FLOATS (ITILE * 1028 + ITILE * 16 * NHF + ITILE * 8 + ITILE)

__global__ void __launch_bounds__(512, 4) gat_fused(
    const float* __restrict__ hmat, const int* __restrict__ adj,
    const float* __restrict__ Wl, const float* __restrict__ Wr,
    const float* __restrict__ attn_w, unsigned int* __restrict__ flags,
    float* __restrict__ out) {
    __shared__ float lds[LDS_FLOATS];  // 24.8 KB (>= 16*HPSTR = 4160 floats)

    const int tid = threadIdx.x;
    const int bx  = blockIdx.x;

    // ================= Part 1: g_l = h@Wl^T, g_r = h@Wr^T =================
    // 1024 tiles = 64 rowgroups(16 rows) x 16 colsets(16 cols); 2 tiles/block.
    // 8 waves, 2 cols/wave; lanes = 16 rows x 4 k-chunks of 64; W broadcast
    // VMEM float4 (L1-hot); packed-fp32 dots; kc folded by shfl.
#pragma unroll 1
    for (int t = bx; t < 1024; t += 512) {
        float* hp = lds;
        const int rg = t & 63;
        const int cs = t >> 6;
        const float4* __restrict__ hsrc = (const float4*)hmat + rg * (16 * 64);
#pragma unroll
        for (int i = 0; i < 2; ++i) {
            const int v = tid + i * 512;      // flat float4 index, 1024 total
            const int row = v >> 6, kq = v & 63;
            *(float4*)(hp + row * HPSTR + kq * 4) = hsrc[v];
        }
        __syncthreads();

        const int lane = tid & 63;
        const int row  = lane & 15;           // 16 rows
        const int kc   = lane >> 4;           // 4 k-chunks of 64
        const int wu   = __builtin_amdgcn_readfirstlane(tid >> 6);  // 0..7
        const int c0   = cs * 16 + wu * 2;    // 2 consecutive cols, same W half
        const float* __restrict__ wb = (c0 < OUT_F) ? (Wl + c0 * IN_F)
                                                    : (Wr + (c0 - OUT_F) * IN_F);
        const float* __restrict__ hrow = hp + row * HPSTR + kc * 64;
        const float* __restrict__ wrow = wb + kc * 64;

        vf2 a0 = {0.f, 0.f}, a1 = {0.f, 0.f};
#pragma unroll 4
        for (int i = 0; i < 16; ++i) {
            const float4 hv = *(const float4*)(hrow + i * 4);
            const vf2 hA = {hv.x, hv.y};
            const vf2 hB = {hv.z, hv.w};
            const float4 w0 = *(const float4*)(wrow + 0 * IN_F + i * 4);
            const float4 w1 = *(const float4*)(wrow + 1 * IN_F + i * 4);
            a0 = hA * (vf2){w0.x, w0.y} + a0;  a0 = hB * (vf2){w0.z, w0.w} + a0;
            a1 = hA * (vf2){w1.x, w1.y} + a1;  a1 = hB * (vf2){w1.z, w1.w} + a1;
        }
        float s0 = a0.x + a0.y, s1 = a1.x + a1.y;
        s0 += __shfl_xor(s0, 16); s0 += __shfl_xor(s0, 32);
        s1 += __shfl_xor(s1, 16); s1 += __shfl_xor(s1, 32);

        if (kc == 0) {
            const int cb = c0 & (OUT_F - 1);
            const int hh = cb >> 5;
            const int f  = cb & 31;           // even -> aligned float2 store
            float* __restrict__ dst = (c0 < OUT_F) ? g_glh : g_grh;
            float2 r; r.x = s0; r.y = s1;
            *(float2*)(dst + (hh * NN + rg * 16 + row) * NHF + f) = r;
        }
        __syncthreads();                      // LDS reuse next tile
    }

    // ================= software grid barrier (512 blocks) =================
    __threadfence();                          // device-scope release
    __syncthreads();
    if (tid == 0)
        __hip_atomic_store(&flags[bx], MAGIC, __ATOMIC_RELEASE,
                           __HIP_MEMORY_SCOPE_AGENT);
    while (__hip_atomic_load(&flags[tid], __ATOMIC_ACQUIRE,
                             __HIP_MEMORY_SCOPE_AGENT) != MAGIC) {
        __builtin_amdgcn_s_sleep(1);
    }
    __syncthreads();
    __threadfence();                          // acquire: invalidate stale lines

    // ================= Part 2: attention, 2 units/block =================
    // 1024 units = 256 i-tiles(4 rows) x 4 heads; unit u = bx, bx+512.
    float (*p_buf)[1028]    = (float(*)[1028])lds;
    float (*part)[16][NHF]  = (float(*)[16][NHF])(lds + ITILE * 1028);
    float (*red)[8]         = (float(*)[8])(lds + ITILE * 1028 + ITILE * 16 * NHF);
    float* l_sh             = lds + ITILE * 1028 + ITILE * 16 * NHF + ITILE * 8;

#pragma unroll 1
    for (int u = bx; u < 1024; u += 512) {
        const int hh = u >> 8;
        const int i0 = (u & 255) * ITILE;

        float lpart[ITILE];
#pragma unroll
        for (int ii = 0; ii < ITILE; ++ii) lpart[ii] = 0.f;

        // ---- Phase A (e + exp + row-sum fused) ----
#pragma unroll 1
        for (int c = 0; c < 2; ++c) {
            const int j = (c << 9) + tid;
            const float* __restrict__ gp = g_glh + (hh * NN + j) * NHF;
            int adjv[ITILE];
#pragma unroll
            for (int ii = 0; ii < ITILE; ++ii) adjv[ii] = adj[(i0 + ii) * NN + j];

            vf2 S2[ITILE];
#pragma unroll
            for (int ii = 0; ii < ITILE; ++ii) S2[ii] = (vf2){0.f, 0.f};
            vf2 alpha2 = {0.f, 0.f};

#pragma unroll
            for (int fh = 0; fh < 2; ++fh) {   // f-half loop: 16 gl floats live
                const int fb = fh << 4;
                vf2 g2[8];
#pragma unroll
                for (int q = 0; q < 4; ++q) {
                    const float4 v = *(const float4*)(gp + fb + (q << 2));
                    g2[2 * q + 0] = (vf2){v.x, v.y};
                    g2[2 * q + 1] = (vf2){v.z, v.w};
                }
#pragma unroll
                for (int k2 = 0; k2 < 8; ++k2) {
                    const vf2 w2 = *(const vf2*)(attn_w + fb + 2 * k2);  // s_load
                    alpha2 = g2[k2] * w2 + alpha2;
                }
#pragma unroll
                for (int ii = 0; ii < ITILE; ++ii) {
                    const float* __restrict__ grp = g_grh + (hh * NN + i0 + ii) * NHF + fb;
                    vf2 acc = S2[ii];
#pragma unroll
                    for (int k2 = 0; k2 < 8; ++k2) {
                        const vf2 s = g2[k2] + *(const vf2*)(grp + 2 * k2);
                        vf2 a; a.x = fabsf(s.x); a.y = fabsf(s.y);
                        acc = a * (*(const vf2*)(attn_w + fb + 2 * k2)) + acc;
                    }
                    S2[ii] = acc;
                }
            }
#pragma unroll
            for (int ii = 0; ii < ITILE; ++ii) {
                const float e = fmaf(0.4f, S2[ii].x + S2[ii].y,
                                     0.6f * (alpha2.x + alpha2.y));
                const float p = adjv[ii] ? __expf(e) : 0.f;
                p_buf[ii][j] = p;
                lpart[ii] += p;
            }
        }

        // ---- row-sum reduction ----
        const int lane = tid & 63, wv = tid >> 6;
#pragma unroll
        for (int ii = 0; ii < ITILE; ++ii) {
            float v = lpart[ii];
#pragma unroll
            for (int d = 32; d > 0; d >>= 1) v += __shfl_xor(v, d);
            if (lane == 0) red[ii][wv] = v;
        }
        __syncthreads();
        if (tid < ITILE) {
            float l = red[tid][0];
#pragma unroll
            for (int w = 1; w < 8; ++w) l += red[tid][w];
            l_sh[tid] = l;
        }
        __syncthreads();

        // ---- Phase C: o[ii,f] = sum_j p * g_r (packed over jj-pairs) ----
        const int f  = tid & 31;
        const int js = tid >> 5;              // 16 j-slices of 64
        const float* __restrict__ gp = g_grh + hh * NN * NHF + f;
        vf2 o2[ITILE];
#pragma unroll
        for (int ii = 0; ii < ITILE; ++ii) o2[ii] = (vf2){0.f, 0.f};
        const int jb = js << 6;
#pragma unroll 4
        for (int jj = 0; jj < 64; jj += 4) {
            const int j = jb + jj;
            const float g0 = gp[(j + 0) * NHF];
            const float g1 = gp[(j + 1) * NHF];
            const float g2 = gp[(j + 2) * NHF];
            const float g3 = gp[(j + 3) * NHF];
            const vf2 gA = {g0, g1};
            const vf2 gB = {g2, g3};
#pragma unroll
            for (int ii = 0; ii < ITILE; ++ii) {
                const float4 p4 = *(const float4*)&p_buf[ii][j];
                o2[ii] = (vf2){p4.x, p4.y} * gA + o2[ii];
                o2[ii] = (vf2){p4.z, p4.w} * gB + o2[ii];
            }
        }
#pragma unroll
        for (int ii = 0; ii < ITILE; ++ii) part[ii][js][f] = o2[ii].x + o2[ii].y;
        __syncthreads();

        if (tid < 32 * ITILE) {
            const int ii = tid >> 5, ff = tid & 31;
            float s0 = 0.f, s1 = 0.f, s2 = 0.f, s3 = 0.f;
#pragma unroll
            for (int k = 0; k < 16; k += 4) {
                s0 += part[ii][k + 0][ff];
                s1 += part[ii][k + 1][ff];
                s2 += part[ii][k + 2][ff];
                s3 += part[ii][k + 3][ff];
            }
            float s = ((s0 + s1) + (s2 + s3)) / l_sh[ii];
            const float r = (s > 0.f) ? s : (__expf(s) - 1.f);
            out[(i0 + ii) * OUT_F + hh * NHF + ff] = r;
        }
        __syncthreads();                      // LDS reuse next unit
    }
}

extern "C" void kernel_launch(void* const* d_in, const int* in_sizes, int n_in,
                              void* d_out, int out_size, void* d_ws, size_t ws_size,
                              hipStream_t stream) {
    const float* hmat = (const float*)d_in[0];
    const int*   adj  = (const int*)d_in[1];
    const float* Wl   = (const float*)d_in[2];
    const float* Wr   = (const float*)d_in[3];
    const float* aw   = (const float*)d_in[4];
    float* o          = (float*)d_out;
    unsigned int* flags = (unsigned int*)d_ws;   // [512]; poison re-arms it

    gat_fused<<<dim3(512), dim3(512), 0, stream>>>(hmat, adj, Wl, Wr, aw,
                                                   flags, o);
}

// Round 18
// 98.621 us; speedup vs baseline: 4.2907x; 4.2907x over previous
//
#include <hip/hip_runtime.h>
#include <math.h>

#define NN 1024
#define IN_F 256
#define OUT_F 128
#define NHEADS 4
#define NHF 32
#define ITILE 4
#define HPSTR 260  // h-tile row stride in dwords. Row term gives banks row*4%32,
                   // chunk term is 0 mod 32 -> every ds_read_b128 across 64 lanes
                   // lands exactly 8 dwords/bank = the b128 floor (conflict-free).

typedef float vf2 __attribute__((ext_vector_type(2)));  // -> v_pk_*_f32 on gfx950

// R17 postmortem: fusion refuted twice. Cooperative launch never executes under
// the harness's graph capture (R10: absmax == max|ref|). Software grid barrier
// passes but costs 4.5x: R13/R17 both had VGPR=64 under a 128 cap (no spill),
// yet FETCH/WRITE ~100-200MB and VALUBusy 3.5% -- the agent-scope fences
// (L2 writeback-invalidate on non-coherent XCD L2s) + agent-scope atomic
// polling force HBM-level round trips for the whole grid. Kernel-boundary
// sync is effectively free by comparison. Reverted to the measured-best R9
// build (99.88us): two kernels, packed fp32, no workspace tricks.
//
// Session accounting: total ~= 41us unconditional harness poison fill (proven
// R14: fills persist even with d_ws untouched) + ~59us kernels/gaps, invariant
// under -40% VALU issue (R5->R9) and 19->50% occupancy (R2->R4).

// K1 v6: g_l = h @ Wl^T, g_r = h @ Wr^T -> [head][row][f] fp32.
// 8-row tiles (8.3 KB LDS), grid 2048 = 128 rowgroups x 16 colsets -> 8 blocks/CU,
// 32 waves/CU. Lanes = 8 rows x 8 k-chunks of 32; W as broadcast VMEM float4;
// dot products in packed fp32 (v_pk_fma_f32); k-chunks folded with 3 shfl_xor.
__global__ void __launch_bounds__(256, 8) glr_gemm(const float* __restrict__ hmat,
                                                   const float* __restrict__ Wl,
                                                   const float* __restrict__ Wr,
                                                   float* __restrict__ glh,
                                                   float* __restrict__ grh) {
    __shared__ float hp[8 * HPSTR];  // 8.3 KB
    const int tid = threadIdx.x;
    const int rg = blockIdx.x & 127;  // 128 row-groups of 8 rows
    const int cs = blockIdx.x >> 7;   // 16 col-sets of 16 cols

    // Stage 8 rows x 256 floats, coalesced.
    const float4* __restrict__ hsrc = (const float4*)hmat + rg * (8 * 64);
#pragma unroll
    for (int i = 0; i < 2; ++i) {
        const int v = tid + i * 256;
        const int row = v >> 6, kq = v & 63;
        *(float4*)(hp + row * HPSTR + kq * 4) = hsrc[v];
    }
    __syncthreads();

    const int lane = tid & 63;
    const int row  = lane & 7;        // 8 rows
    const int kc   = lane >> 3;       // 8 k-chunks of 32 floats
    const int wu   = __builtin_amdgcn_readfirstlane(tid >> 6);
    const int c0   = cs * 16 + wu * 4;
    const float* __restrict__ wb = (c0 < OUT_F) ? (Wl + c0 * IN_F)
                                                : (Wr + (c0 - OUT_F) * IN_F);
    const float* __restrict__ hrow = hp + row * HPSTR + kc * 32;
    const float* __restrict__ wrow = wb + kc * 32;

    vf2 a0 = {0.f, 0.f}, a1 = {0.f, 0.f}, a2 = {0.f, 0.f}, a3 = {0.f, 0.f};
#pragma unroll 2
    for (int i = 0; i < 8; ++i) {
        const float4 hv = *(const float4*)(hrow + i * 4);
        const vf2 hA = {hv.x, hv.y};
        const vf2 hB = {hv.z, hv.w};
        const float4 w0 = *(const float4*)(wrow + 0 * IN_F + i * 4);
        const float4 w1 = *(const float4*)(wrow + 1 * IN_F + i * 4);
        const float4 w2 = *(const float4*)(wrow + 2 * IN_F + i * 4);
        const float4 w3 = *(const float4*)(wrow + 3 * IN_F + i * 4);
        a0 = hA * (vf2){w0.x, w0.y} + a0;  a0 = hB * (vf2){w0.z, w0.w} + a0;
        a1 = hA * (vf2){w1.x, w1.y} + a1;  a1 = hB * (vf2){w1.z, w1.w} + a1;
        a2 = hA * (vf2){w2.x, w2.y} + a2;  a2 = hB * (vf2){w2.z, w2.w} + a2;
        a3 = hA * (vf2){w3.x, w3.y} + a3;  a3 = hB * (vf2){w3.z, w3.w} + a3;
    }
    float s0 = a0.x + a0.y, s1 = a1.x + a1.y, s2 = a2.x + a2.y, s3 = a3.x + a3.y;
    // fold the 8 k-chunks (lane bits 3,4,5)
#pragma unroll
    for (int d = 8; d <= 32; d <<= 1) {
        s0 += __shfl_xor(s0, d);
        s1 += __shfl_xor(s1, d);
        s2 += __shfl_xor(s2, d);
        s3 += __shfl_xor(s3, d);
    }

    if (kc == 0) {
        const int cb = c0 & (OUT_F - 1);
        const int hh = cb >> 5;
        const int f  = cb & 31;               // multiple of 4 -> aligned float4 store
        float* __restrict__ dst = (c0 < OUT_F) ? glh : grh;
        float4 r; r.x = s0; r.y = s1; r.z = s2; r.w = s3;
        *(float4*)(dst + (hh * NN + rg * 8 + row) * NHF + f) = r;
    }
}

// K2 v6: one block per (i-tile of 4, head); 512 thr = 8 waves; 4 blocks/CU,
// 32 waves/CU, VGPR<=64 (launch_bounds(512,8)), no scratch (live ~45 regs).
// Phase A: f-half loop (g2[8] live) with PACKED fp32: per 2 f-slots
// pk_add + 2x v_and(abs) + pk_fma; alpha packed too. Phase C: R0 shape
// (f <-> 32 lanes, 16 j-slices of 64, sequential j), packed over jj-pairs.
__global__ void __launch_bounds__(512, 8) gat_main(const float* __restrict__ glh,
                                                   const float* __restrict__ grh,
                                                   const int* __restrict__ adj,
                                                   const float* __restrict__ attn_w,
                                                   float* __restrict__ out) {
    const int hh  = blockIdx.y;
    const int i0  = blockIdx.x * ITILE;
    const int tid = threadIdx.x;

    __shared__ float p_buf[ITILE][1028];   // stride%32==4 -> optimal b128 banking
    __shared__ float part[ITILE][16][NHF]; // [ii][j-slice][f]
    __shared__ float red[ITILE][8];
    __shared__ float l_sh[ITILE];

    float lpart[ITILE];
#pragma unroll
    for (int ii = 0; ii < ITILE; ++ii) lpart[ii] = 0.f;

    // ---- Phase A (e + exp + row-sum fused) ----
#pragma unroll 1
    for (int c = 0; c < 2; ++c) {
        const int j = (c << 9) + tid;
        const float* __restrict__ gp = glh + (hh * NN + j) * NHF;
        int adjv[ITILE];
#pragma unroll
        for (int ii = 0; ii < ITILE; ++ii) adjv[ii] = adj[(i0 + ii) * NN + j];

        vf2 S2[ITILE];
#pragma unroll
        for (int ii = 0; ii < ITILE; ++ii) S2[ii] = (vf2){0.f, 0.f};
        vf2 alpha2 = {0.f, 0.f};

#pragma unroll
        for (int fh = 0; fh < 2; ++fh) {       // f-half loop: only 16 gl floats live
            const int fb = fh << 4;
            vf2 g2[8];
#pragma unroll
            for (int q = 0; q < 4; ++q) {
                const float4 v = *(const float4*)(gp + fb + (q << 2));
                g2[2 * q + 0] = (vf2){v.x, v.y};
                g2[2 * q + 1] = (vf2){v.z, v.w};
            }
#pragma unroll
            for (int k2 = 0; k2 < 8; ++k2) {
                const vf2 w2 = *(const vf2*)(attn_w + fb + 2 * k2);   // s_load
                alpha2 = g2[k2] * w2 + alpha2;
            }
#pragma unroll
            for (int ii = 0; ii < ITILE; ++ii) {
                const float* __restrict__ grp = grh + (hh * NN + i0 + ii) * NHF + fb;  // uniform -> s_load
                vf2 acc = S2[ii];
#pragma unroll
                for (int k2 = 0; k2 < 8; ++k2) {
                    const vf2 s = g2[k2] + *(const vf2*)(grp + 2 * k2);
                    vf2 a; a.x = fabsf(s.x); a.y = fabsf(s.y);
                    acc = a * (*(const vf2*)(attn_w + fb + 2 * k2)) + acc;
                }
                S2[ii] = acc;
            }
        }
#pragma unroll
        for (int ii = 0; ii < ITILE; ++ii) {
            const float e = fmaf(0.4f, S2[ii].x + S2[ii].y,
                                 0.6f * (alpha2.x + alpha2.y));
            const float p = adjv[ii] ? __expf(e) : 0.f;
            p_buf[ii][j] = p;
            lpart[ii] += p;
        }
    }

    // ---- row-sum reduction ----
    const int lane = tid & 63, wv = tid >> 6;
#pragma unroll
    for (int ii = 0; ii < ITILE; ++ii) {
        float v = lpart[ii];
#pragma unroll
        for (int d = 32; d > 0; d >>= 1) v += __shfl_xor(v, d);
        if (lane == 0) red[ii][wv] = v;
    }
    __syncthreads();
    if (tid < ITILE) {
        float l = red[tid][0];
#pragma unroll
        for (int w = 1; w < 8; ++w) l += red[tid][w];
        l_sh[tid] = l;
    }
    __syncthreads();

    // ---- Phase C: o[ii,f] = sum_j p * g_r (packed over jj-pairs) ----
    const int f  = tid & 31;
    const int js = tid >> 5;                  // 16 j-slices of 64
    const float* __restrict__ gp = grh + hh * NN * NHF + f;
    vf2 o2[ITILE];
#pragma unroll
    for (int ii = 0; ii < ITILE; ++ii) o2[ii] = (vf2){0.f, 0.f};
    const int jb = js << 6;
#pragma unroll 4
    for (int jj = 0; jj < 64; jj += 4) {
        const int j = jb + jj;
        const float g0 = gp[(j + 0) * NHF];
        const float g1 = gp[(j + 1) * NHF];
        const float g2 = gp[(j + 2) * NHF];
        const float g3 = gp[(j + 3) * NHF];
        const vf2 gA = {g0, g1};
        const vf2 gB = {g2, g3};
#pragma unroll
        for (int ii = 0; ii < ITILE; ++ii) {
            const float4 p4 = *(const float4*)&p_buf[ii][j];
            o2[ii] = (vf2){p4.x, p4.y} * gA + o2[ii];
            o2[ii] = (vf2){p4.z, p4.w} * gB + o2[ii];
        }
    }
#pragma unroll
    for (int ii = 0; ii < ITILE; ++ii) part[ii][js][f] = o2[ii].x + o2[ii].y;
    __syncthreads();

    if (tid < 32 * ITILE) {
        const int ii = tid >> 5, ff = tid & 31;
        float s0 = 0.f, s1 = 0.f, s2 = 0.f, s3 = 0.f;
#pragma unroll
        for (int k = 0; k < 16; k += 4) {
            s0 += part[ii][k + 0][ff];
            s1 += part[ii][k + 1][ff];
            s2 += part[ii][k + 2][ff];
            s3 += part[ii][k + 3][ff];
        }
        float s = ((s0 + s1) + (s2 + s3)) / l_sh[ii];
        const float r = (s > 0.f) ? s : (__expf(s) - 1.f);
        out[(i0 + ii) * OUT_F + hh * NHF + ff] = r;
    }
}

extern "C" void kernel_launch(void* const* d_in, const int* in_sizes, int n_in,
                              void* d_out, int out_size, void* d_ws, size_t ws_size,
                              hipStream_t stream) {
    const float* hmat = (const float*)d_in[0];
    const int*   adj  = (const int*)d_in[1];
    const float* Wl   = (const float*)d_in[2];
    const float* Wr   = (const float*)d_in[3];
    const float* aw   = (const float*)d_in[4];
    float* o          = (float*)d_out;

    float* glh = (float*)d_ws;                 // [4][1024][32]
    float* grh = glh + NHEADS * NN * NHF;      // [4][1024][32]

    glr_gemm<<<dim3(2048), dim3(256), 0, stream>>>(hmat, Wl, Wr, glh, grh);
    gat_main<<<dim3(NN / ITILE, NHEADS), dim3(512), 0, stream>>>(glh, grh, adj, aw, o);
}